// Round 19
// baseline (619.796 us; speedup 1.0000x reference)
//
#include <hip/hip_runtime.h>
#include <hip/hip_bf16.h>
#include <stdint.h>

typedef __attribute__((ext_vector_type(8))) short short8;
typedef __attribute__((ext_vector_type(4))) float f32x4;

#define NN 50000
#define NNP 50048
#define NE 800000
#define SCAN_B 196   // ceil(50000/256)

__device__ __forceinline__ unsigned short f2bf(float f){
  union { unsigned int i; float f; } v; v.f = f;
  unsigned int u = v.i;
  u += 0x7fffu + ((u >> 16) & 1u);
  return (unsigned short)(u >> 16);
}

// fast silu: x * rcp(1+exp(-x))
__device__ __forceinline__ float fast_silu(float v){
  return v * __builtin_amdgcn_rcpf(1.f + __expf(-v));
}

// Detect whether edge_index is int64 (high 32-bit words all zero) or int32.
__global__ void detect_idx(const int* __restrict__ raw, int* __restrict__ flag){
  if (threadIdx.x == 0 && blockIdx.x == 0){
    int s = 0;
#pragma unroll
    for (int k = 1; k < 256; k += 2) s |= raw[k];
    *flag = (s == 0) ? 1 : 0;
  }
}

__device__ __forceinline__ int load_src(const int* ei, int is64, int e){
  return is64 ? ei[2 * e] : ei[e];
}
__device__ __forceinline__ int load_dst(const int* ei, int is64, int e){
  return is64 ? ei[2 * NE + 2 * e] : ei[NE + e];
}

// CSR pass 1: histogram of dst
__global__ void hist_kernel(const int* __restrict__ ei, const int* __restrict__ idxflag,
                            int* __restrict__ cnt){
  int e = blockIdx.x * 256 + threadIdx.x;
  if (e >= NE) return;
  atomicAdd(&cnt[load_dst(ei, *idxflag, e)], 1);
}

// Parallel scan, stage 1: per-block sums of 256 cnt entries.
__global__ void psum1(const int* __restrict__ cnt, int* __restrict__ bsum){
  __shared__ int ws[4];
  const int tid = threadIdx.x, lane = tid & 63, wid = tid >> 6;
  const int i = blockIdx.x * 256 + tid;
  int v = (i < NN) ? cnt[i] : 0;
#pragma unroll
  for (int o = 32; o >= 1; o >>= 1) v += __shfl_xor(v, o);
  if (lane == 0) ws[wid] = v;
  __syncthreads();
  if (tid == 0) bsum[blockIdx.x] = ws[0] + ws[1] + ws[2] + ws[3];
}

// Parallel scan, stage 2: exclusive scan of SCAN_B block sums.
__global__ void psum2(const int* __restrict__ bsum, int* __restrict__ boff){
  __shared__ int ws[4];
  const int tid = threadIdx.x, lane = tid & 63, wid = tid >> 6;
  int v = (tid < SCAN_B) ? bsum[tid] : 0;
  int s = v;
#pragma unroll
  for (int o = 1; o < 64; o <<= 1){
    int t = __shfl_up(s, o);
    if (lane >= o) s += t;
  }
  if (lane == 63) ws[wid] = s;
  __syncthreads();
  int add = 0;
#pragma unroll
  for (int q = 0; q < 4; ++q) add += (q < wid) ? ws[q] : 0;
  if (tid < SCAN_B) boff[tid] = add + s - v;   // exclusive
}

// Parallel scan, stage 3: writes off[i+1] (inclusive) AND cursor[i] (exclusive).
__global__ void psum3(const int* __restrict__ cnt, const int* __restrict__ boff,
                      int* __restrict__ off, int* __restrict__ cursor){
  __shared__ int ws[4];
  const int tid = threadIdx.x, lane = tid & 63, wid = tid >> 6;
  const int i = blockIdx.x * 256 + tid;
  int v = (i < NN) ? cnt[i] : 0;
  int s = v;
#pragma unroll
  for (int o = 1; o < 64; o <<= 1){
    int t = __shfl_up(s, o);
    if (lane >= o) s += t;
  }
  if (lane == 63) ws[wid] = s;
  __syncthreads();
  int add = boff[blockIdx.x];
#pragma unroll
  for (int q = 0; q < 4; ++q) add += (q < wid) ? ws[q] : 0;
  if (i < NN){
    off[i + 1] = add + s;
    cursor[i]  = add + s - v;   // exclusive prefix
  }
  if (i == 0) off[0] = 0;
}

// CSR pass 3: scatter full edge record {e, src, dst} by dst order.
__global__ void scatter_kernel(const int* __restrict__ ei, const int* __restrict__ idxflag,
                               int* __restrict__ cursor, int4* __restrict__ edata){
  int e = blockIdx.x * 256 + threadIdx.x;
  if (e >= NE) return;
  const int is64 = *idxflag;
  const int sn = load_src(ei, is64, e);
  const int dn = load_dst(ei, is64, e);
  const int pos = atomicAdd(&cursor[dn], 1);
  edata[pos] = make_int4(e, sn, dn, 0);
}

// Fused repack of all 6 weights into bf16 MFMA B-fragment layout.
__global__ void repack_all(
    const float* __restrict__ ew1, const float* __restrict__ ew2,
    const float* __restrict__ ewr, const float* __restrict__ nw1,
    const float* __restrict__ nw2, const float* __restrict__ nwr,
    unsigned short* __restrict__ rew1, unsigned short* __restrict__ rew2,
    unsigned short* __restrict__ rewr, unsigned short* __restrict__ rnw1,
    unsigned short* __restrict__ rnw2, unsigned short* __restrict__ rnwr)
{
  const int b = blockIdx.x;
  const float* W; unsigned short* out; int K, N, base;
  if (b < 48)       { W = ew1; out = rew1; K = 384; N = 256; base = 0;   }
  else if (b < 64)  { W = ew2; out = rew2; K = 256; N = 128; base = 48;  }
  else if (b < 88)  { W = ewr; out = rewr; K = 384; N = 128; base = 64;  }
  else if (b < 120) { W = nw1; out = rnw1; K = 256; N = 256; base = 88;  }
  else if (b < 136) { W = nw2; out = rnw2; K = 256; N = 128; base = 120; }
  else              { W = nwr; out = rnwr; K = 256; N = 128; base = 136; }
  int t = (b - base) * 256 + threadIdx.x;
  int lane = t & 63;
  int frag = t >> 6;
  int nts = N >> 4;
  int nt = frag % nts;
  int kt = frag / nts;
  if (kt >= (K >> 5)) return;
  int r0 = kt * 32 + 8 * (lane >> 4);
  int c  = nt * 16 + (lane & 15);
  short8 v;
#pragma unroll
  for (int j = 0; j < 8; ++j) v[j] = (short)f2bf(W[(size_t)(r0 + j) * N + c]);
  *(short8*)(out + (size_t)t * 8) = v;
}

__device__ __forceinline__ short8 cvt8(const float* p){
  f32x4 a = *(const f32x4*)(p);
  f32x4 b = *(const f32x4*)(p + 4);
  union { short8 s; __hip_bfloat162 h[4]; } u;
  u.h[0] = __float22bfloat162_rn(make_float2(a[0], a[1]));
  u.h[1] = __float22bfloat162_rn(make_float2(a[2], a[3]));
  u.h[2] = __float22bfloat162_rn(make_float2(b[0], b[1]));
  u.h[3] = __float22bfloat162_rn(make_float2(b[2], b[3]));
  return u.s;
}

// Bijective XCD-chunked swizzle (m204 form)
__device__ __forceinline__ int xcd_swizzle(int bid, int nwg){
  const int q = nwg >> 3, r = nwg & 7;
  const int xcd = bid & 7, idx = bid >> 3;
  return (xcd < r) ? xcd * (q + 1) + idx : r * (q + 1) + (xcd - r) * q + idx;
}

// ---------------- Edge kernel (R18 + half-tile staging pipeline) -----------
// Stage h0 (ks 0..5) -> barrier -> issue h1 gather (latency hides under the
// ks0..5 MFMA stream at prio 1) -> barrier -> ks 6..11. h0/h1 LDS disjoint.
__global__ __launch_bounds__(512, 4) void edge_kernel(
    const float* __restrict__ x,
    const float* __restrict__ ea,
    const int4* __restrict__ edata,
    const unsigned short* __restrict__ rw1,
    const unsigned short* __restrict__ rw2,
    const unsigned short* __restrict__ rwr,
    const float* __restrict__ b1,
    const float* __restrict__ b2,
    const float* __restrict__ br,
    const float* __restrict__ gam,
    const float* __restrict__ bet,
    float* __restrict__ oute,
    float* __restrict__ agg)
{
  extern __shared__ char smem[];
  unsigned short* A = (unsigned short*)smem;        // [4][12][64][8] bf16 = 48KB
  unsigned short* H = (unsigned short*)smem;        // [4][8][64][8]  = 32KB (alias)
  float* pf2    = (float*)smem;                     // [64 rows][132] (alias)
  float* pfstat = (float*)(smem + 34816);           // [64][2]
  int*   dst_lds  = (int*)(smem + 49152);           // [64]  beyond A
  int*   eidx_lds = (int*)(smem + 49408);           // [64]  beyond A

  const int tid  = threadIdx.x;
  const int lane = tid & 63;
  const int w    = tid >> 6;
  const int q0   = xcd_swizzle(blockIdx.x, NE / 64) * 64;

  const int row = lane;
  const int4 ed = edata[q0 + row];    // single 16B load: {e, sn, dn, 0}
  const int e = ed.x, sn = ed.y, dn = ed.z;
  if (tid < 64){ dst_lds[row] = dn; eidx_lds[row] = e; }
  const int m   = row >> 4;
  const int rl  = row & 15;

  // stage h0: segs 0..23 (ks 0..5)
#pragma unroll
  for (int it = 0; it < 3; ++it){
    const int seg = w + 8 * it;
    const float* p;
    if (seg < 16)      p = ea + (size_t)e  * 128 + seg * 8;
    else               p = x  + (size_t)sn * 128 + (seg - 16) * 8;
    short8 v = cvt8(p);
    const int ks = seg >> 2;
    const int lp = rl + 16 * (seg & 3);
    *(short8*)(A + (((m * 12 + ks) * 64) + lp) * 8) = v;
  }

  short8 cb1[2], cbr, nb1[2], nbr;
#pragma unroll
  for (int nti = 0; nti < 2; ++nti)
    cb1[nti] = *(const short8*)(rw1 + ((size_t)((w * 2 + nti) * 64 + lane)) * 8);
  cbr = *(const short8*)(rwr + ((size_t)(w * 64 + lane)) * 8);

  __syncthreads();   // h0 ready

  // issue h1 staging now: segs 24..47 (ks 6..11) — hides under GEMM1-h0
#pragma unroll
  for (int it = 3; it < 6; ++it){
    const int seg = w + 8 * it;
    const float* p;
    if (seg < 32) p = x + (size_t)sn * 128 + (seg - 16) * 8;
    else          p = x + (size_t)dn * 128 + (seg - 32) * 8;
    short8 v = cvt8(p);
    const int ks = seg >> 2;
    const int lp = rl + 16 * (seg & 3);
    *(short8*)(A + (((m * 12 + ks) * 64) + lp) * 8) = v;
  }

  f32x4 acc1[2][4];
  f32x4 accr[4];
#pragma unroll
  for (int i = 0; i < 2; ++i)
#pragma unroll
    for (int j = 0; j < 4; ++j) acc1[i][j] = (f32x4){0.f,0.f,0.f,0.f};
#pragma unroll
  for (int j = 0; j < 4; ++j) accr[j] = (f32x4){0.f,0.f,0.f,0.f};

  // GEMM1 part 1: ks 0..5 on h0
#pragma unroll
  for (int ks = 0; ks < 6; ++ks){
#pragma unroll
    for (int nti = 0; nti < 2; ++nti)
      nb1[nti] = *(const short8*)(rw1 + ((size_t)(((ks + 1) * 16 + w * 2 + nti) * 64 + lane)) * 8);
    nbr = *(const short8*)(rwr + ((size_t)(((ks + 1) * 8 + w) * 64 + lane)) * 8);
    short8 af[4];
#pragma unroll
    for (int mm = 0; mm < 4; ++mm)
      af[mm] = *(const short8*)(A + (((mm * 12 + ks) * 64) + lane) * 8);
    __builtin_amdgcn_s_setprio(1);
#pragma unroll
    for (int nti = 0; nti < 2; ++nti)
#pragma unroll
      for (int mm = 0; mm < 4; ++mm)
        acc1[nti][mm] = __builtin_amdgcn_mfma_f32_16x16x32_bf16(af[mm], cb1[nti], acc1[nti][mm], 0, 0, 0);
#pragma unroll
    for (int mm = 0; mm < 4; ++mm)
      accr[mm] = __builtin_amdgcn_mfma_f32_16x16x32_bf16(af[mm], cbr, accr[mm], 0, 0, 0);
    __builtin_amdgcn_s_setprio(0);
#pragma unroll
    for (int nti = 0; nti < 2; ++nti) cb1[nti] = nb1[nti];
    cbr = nbr;
  }

  __syncthreads();   // h1 ready (stores issued long before ks0..5 completed)

  // GEMM1 part 2: ks 6..11 on h1
#pragma unroll
  for (int ks = 6; ks < 12; ++ks){
    if (ks < 11){
#pragma unroll
      for (int nti = 0; nti < 2; ++nti)
        nb1[nti] = *(const short8*)(rw1 + ((size_t)(((ks + 1) * 16 + w * 2 + nti) * 64 + lane)) * 8);
      nbr = *(const short8*)(rwr + ((size_t)(((ks + 1) * 8 + w) * 64 + lane)) * 8);
    }
    short8 af[4];
#pragma unroll
    for (int mm = 0; mm < 4; ++mm)
      af[mm] = *(const short8*)(A + (((mm * 12 + ks) * 64) + lane) * 8);
    __builtin_amdgcn_s_setprio(1);
#pragma unroll
    for (int nti = 0; nti < 2; ++nti)
#pragma unroll
      for (int mm = 0; mm < 4; ++mm)
        acc1[nti][mm] = __builtin_amdgcn_mfma_f32_16x16x32_bf16(af[mm], cb1[nti], acc1[nti][mm], 0, 0, 0);
#pragma unroll
    for (int mm = 0; mm < 4; ++mm)
      accr[mm] = __builtin_amdgcn_mfma_f32_16x16x32_bf16(af[mm], cbr, accr[mm], 0, 0, 0);
    __builtin_amdgcn_s_setprio(0);
    if (ks < 11){
#pragma unroll
      for (int nti = 0; nti < 2; ++nti) cb1[nti] = nb1[nti];
      cbr = nbr;
    }
  }

  short8 cb2, nb2;
  cb2 = *(const short8*)(rw2 + ((size_t)(w * 64 + lane)) * 8);

  __syncthreads();   // ALL waves done reading A; safe to overwrite with H

#pragma unroll
  for (int nti = 0; nti < 2; ++nti){
    const int nt  = w * 2 + nti;
    const int col = nt * 16 + (lane & 15);
    const float bias = b1[col];
    const int ks  = nt >> 1;
    const int lpb = 4 * (lane >> 4) + 16 * (2 * (nt & 1) + ((lane >> 3) & 1));
    const int t   = lane & 7;
#pragma unroll
    for (int mm = 0; mm < 4; ++mm){
#pragma unroll
      for (int r = 0; r < 4; ++r){
        const float v = fast_silu(acc1[nti][mm][r] + bias);
        H[(((mm * 8 + ks) * 64) + lpb + r) * 8 + t] = f2bf(v);
      }
    }
  }
  __syncthreads();

#pragma unroll
  for (int ks = 0; ks < 8; ++ks){
    if (ks < 7)
      nb2 = *(const short8*)(rw2 + ((size_t)(((ks + 1) * 8 + w) * 64 + lane)) * 8);
    short8 hf[4];
#pragma unroll
    for (int mm = 0; mm < 4; ++mm)
      hf[mm] = *(const short8*)(H + (((mm * 8 + ks) * 64) + lane) * 8);
    __builtin_amdgcn_s_setprio(1);
#pragma unroll
    for (int mm = 0; mm < 4; ++mm)
      accr[mm] = __builtin_amdgcn_mfma_f32_16x16x32_bf16(hf[mm], cb2, accr[mm], 0, 0, 0);
    __builtin_amdgcn_s_setprio(0);
    if (ks < 7) cb2 = nb2;
  }

  const int l15 = lane & 15;
  const int g   = lane >> 4;
  const int col = w * 16 + l15;
  const float bb  = b2[col] + br[col];
  const float gma = gam[col];
  const float bt  = bet[col];
  float vout[4][4];
#pragma unroll
  for (int mm = 0; mm < 4; ++mm)
#pragma unroll
    for (int r = 0; r < 4; ++r)
      vout[mm][r] = accr[mm][r] + bb;

  __syncthreads();
#pragma unroll
  for (int mm = 0; mm < 4; ++mm)
#pragma unroll
    for (int r = 0; r < 4; ++r)
      pf2[(mm * 16 + g * 4 + r) * 132 + col] = vout[mm][r];
  __syncthreads();

  {
    const int srow = tid >> 3;
    const int cb  = tid & 7;
    const float* pr = pf2 + srow * 132 + cb * 16;
    f32x4 a0 = *(const f32x4*)(pr);
    f32x4 a1 = *(const f32x4*)(pr + 4);
    f32x4 a2 = *(const f32x4*)(pr + 8);
    f32x4 a3 = *(const f32x4*)(pr + 12);
    float s1 = 0.f, s2 = 0.f;
#pragma unroll
    for (int j = 0; j < 4; ++j){
      s1 += a0[j] + a1[j] + a2[j] + a3[j];
      s2 += a0[j]*a0[j] + a1[j]*a1[j] + a2[j]*a2[j] + a3[j]*a3[j];
    }
#pragma unroll
    for (int off = 1; off < 8; off <<= 1){
      s1 += __shfl_xor(s1, off);
      s2 += __shfl_xor(s2, off);
    }
    if (cb == 0){
      const float mean = s1 * (1.f/128.f);
      const float var  = s2 * (1.f/128.f) - mean * mean;
      pfstat[srow * 2 + 0] = mean;
      pfstat[srow * 2 + 1] = rsqrtf(var + 1e-5f);
    }
  }
  __syncthreads();

  // apply LN ONCE: nt-store oute + post-LN back to pf2
#pragma unroll
  for (int mm = 0; mm < 4; ++mm)
#pragma unroll
    for (int r = 0; r < 4; ++r){
      const int srow = mm * 16 + g * 4 + r;
      const float2 st = *(const float2*)(pfstat + srow * 2);
      const float val = (vout[mm][r] - st.x) * st.y * gma + bt;
      __builtin_nontemporal_store(val, &oute[(size_t)eidx_lds[srow] * 128 + col]);
      pf2[srow * 132 + col] = val;
    }
  __syncthreads();

  { // segment reduction: pure adds over post-LN pf2
    const int colA = tid & 127;
    const int q4   = tid >> 7;
    int   cur = dst_lds[q4 * 16];
    float run = 0.f;
#pragma unroll
    for (int j = 0; j < 16; ++j){
      const int srow = q4 * 16 + j;
      const int dnn = dst_lds[srow];
      const float v = pf2[srow * 132 + colA];
      if (dnn != cur){
        atomicAdd(&agg[(size_t)cur * 128 + colA], run);
        run = 0.f; cur = dnn;
      }
      run += v;
    }
    atomicAdd(&agg[(size_t)cur * 128 + colA], run);
  }
}

// ---------------- Node kernel (R18 structure, unchanged) -------------------
__global__ __launch_bounds__(512, 4) void node_kernel(
    const float* __restrict__ x,
    const float* __restrict__ agg,
    const unsigned short* __restrict__ rw1,
    const unsigned short* __restrict__ rw2,
    const unsigned short* __restrict__ rwr,
    const float* __restrict__ b1,
    const float* __restrict__ b2,
    const float* __restrict__ br,
    const float* __restrict__ gam,
    const float* __restrict__ bet,
    float* __restrict__ outx)
{
  extern __shared__ char smem[];
  unsigned short* A = (unsigned short*)smem;
  unsigned short* H = (unsigned short*)smem;
  float* pf2    = (float*)smem;
  float* pfstat = (float*)(smem + 34816);

  const int tid  = threadIdx.x;
  const int lane = tid & 63;
  const int w    = tid >> 6;
  const int n0   = blockIdx.x * 64;

  {
    const int row = lane;
    const int n   = n0 + row;
    const bool ok = (n < NN);
    const int m   = row >> 4;
    const int rl  = row & 15;
#pragma unroll
    for (int it = 0; it < 4; ++it){
      const int seg = w + 8 * it;
      short8 v;
      if (!ok){
        v = (short8){0,0,0,0,0,0,0,0};
      } else {
        const float* p = (seg < 16) ? (x + (size_t)n * 128 + seg * 8)
                                    : (agg + (size_t)n * 128 + (seg - 16) * 8);
        v = cvt8(p);
      }
      const int ks = seg >> 2;
      const int lp = rl + 16 * (seg & 3);
      *(short8*)(A + (((m * 8 + ks) * 64) + lp) * 8) = v;
    }
  }

  short8 cb1[2], cbr, nb1[2], nbr;
#pragma unroll
  for (int nti = 0; nti < 2; ++nti)
    cb1[nti] = *(const short8*)(rw1 + ((size_t)((w * 2 + nti) * 64 + lane)) * 8);
  cbr = *(const short8*)(rwr + ((size_t)(w * 64 + lane)) * 8);

  __syncthreads();

  f32x4 acc1[2][4];
  f32x4 accr[4];
#pragma unroll
  for (int i = 0; i < 2; ++i)
#pragma unroll
    for (int j = 0; j < 4; ++j) acc1[i][j] = (f32x4){0.f,0.f,0.f,0.f};
#pragma unroll
  for (int j = 0; j < 4; ++j) accr[j] = (f32x4){0.f,0.f,0.f,0.f};

#pragma unroll
  for (int ks = 0; ks < 8; ++ks){
    if (ks < 7){
#pragma unroll
      for (int nti = 0; nti < 2; ++nti)
        nb1[nti] = *(const short8*)(rw1 + ((size_t)(((ks + 1) * 16 + w * 2 + nti) * 64 + lane)) * 8);
      nbr = *(const short8*)(rwr + ((size_t)(((ks + 1) * 8 + w) * 64 + lane)) * 8);
    }
    short8 af[4];
#pragma unroll
    for (int m = 0; m < 4; ++m)
      af[m] = *(const short8*)(A + (((m * 8 + ks) * 64) + lane) * 8);
    __builtin_amdgcn_s_setprio(1);
#pragma unroll
    for (int nti = 0; nti < 2; ++nti)
#pragma unroll
      for (int m = 0; m < 4; ++m)
        acc1[nti][m] = __builtin_amdgcn_mfma_f32_16x16x32_bf16(af[m], cb1[nti], acc1[nti][m], 0, 0, 0);
#pragma unroll
    for (int m = 0; m < 4; ++m)
      accr[m] = __builtin_amdgcn_mfma_f32_16x16x32_bf16(af[m], cbr, accr[m], 0, 0, 0);
    __builtin_amdgcn_s_setprio(0);
    if (ks < 7){
#pragma unroll
      for (int nti = 0; nti < 2; ++nti) cb1[nti] = nb1[nti];
      cbr = nbr;
    }
  }

  short8 cb2, nb2;
  cb2 = *(const short8*)(rw2 + ((size_t)(w * 64 + lane)) * 8);

  __syncthreads();

#pragma unroll
  for (int nti = 0; nti < 2; ++nti){
    const int nt  = w * 2 + nti;
    const int col = nt * 16 + (lane & 15);
    const float bias = b1[col];
    const int ks  = nt >> 1;
    const int lpb = 4 * (lane >> 4) + 16 * (2 * (nt & 1) + ((lane >> 3) & 1));
    const int t   = lane & 7;
#pragma unroll
    for (int m = 0; m < 4; ++m){
#pragma unroll
      for (int r = 0; r < 4; ++r){
        const float v = fast_silu(acc1[nti][m][r] + bias);
        H[(((m * 8 + ks) * 64) + lpb + r) * 8 + t] = f2bf(v);
      }
    }
  }
  __syncthreads();

#pragma unroll
  for (int ks = 0; ks < 8; ++ks){
    if (ks < 7)
      nb2 = *(const short8*)(rw2 + ((size_t)(((ks + 1) * 8 + w) * 64 + lane)) * 8);
    short8 hf[4];
#pragma unroll
    for (int m = 0; m < 4; ++m)
      hf[m] = *(const short8*)(H + (((m * 8 + ks) * 64) + lane) * 8);
    __builtin_amdgcn_s_setprio(1);
#pragma unroll
    for (int m = 0; m < 4; ++m)
      accr[m] = __builtin_amdgcn_mfma_f32_16x16x32_bf16(hf[m], cb2, accr[m], 0, 0, 0);
    __builtin_amdgcn_s_setprio(0);
    if (ks < 7) cb2 = nb2;
  }

  const int l15 = lane & 15;
  const int g   = lane >> 4;
  const int col = w * 16 + l15;
  const float bb  = b2[col] + br[col];
  const float gma = gam[col];
  const float bt  = bet[col];
  float vout[4][4];
#pragma unroll
  for (int m = 0; m < 4; ++m)
#pragma unroll
    for (int r = 0; r < 4; ++r)
      vout[m][r] = accr[m][r] + bb;

  __syncthreads();
#pragma unroll
  for (int m = 0; m < 4; ++m)
#pragma unroll
    for (int r = 0; r < 4; ++r)
      pf2[(m * 16 + g * 4 + r) * 132 + col] = vout[m][r];
  __syncthreads();

  {
    const int row = tid >> 3;
    const int cb  = tid & 7;
    const float* pr = pf2 + row * 132 + cb * 16;
    f32x4 a0 = *(const f32x4*)(pr);
    f32x4 a1 = *(const f32x4*)(pr + 4);
    f32x4 a2 = *(const f32x4*)(pr + 8);
    f32x4 a3 = *(const f32x4*)(pr + 12);
    float s1 = 0.f, s2 = 0.f;
#pragma unroll
    for (int j = 0; j < 4; ++j){
      s1 += a0[j] + a1[j] + a2[j] + a3[j];
      s2 += a0[j]*a0[j] + a1[j]*a1[j] + a2[j]*a2[j] + a3[j]*a3[j];
    }
#pragma unroll
    for (int off2 = 1; off2 < 8; off2 <<= 1){
      s1 += __shfl_xor(s1, off2);
      s2 += __shfl_xor(s2, off2);
    }
    if (cb == 0){
      const float mean = s1 * (1.f/128.f);
      const float var  = s2 * (1.f/128.f) - mean * mean;
      pfstat[row * 2 + 0] = mean;
      pfstat[row * 2 + 1] = rsqrtf(var + 1e-5f);
    }
  }
  __syncthreads();

#pragma unroll
  for (int m = 0; m < 4; ++m)
#pragma unroll
    for (int r = 0; r < 4; ++r){
      const int row = m * 16 + g * 4 + r;
      const int n = n0 + row;
      if (n >= NN) continue;
      const float2 st = *(const float2*)(pfstat + row * 2);
      const float val = (vout[m][r] - st.x) * st.y * gma + bt;
      __builtin_nontemporal_store(val, &outx[(size_t)n * 128 + col]);
    }
}

extern "C" void kernel_launch(void* const* d_in, const int* in_sizes, int n_in,
                              void* d_out, int out_size, void* d_ws, size_t ws_size,
                              hipStream_t stream)
{
  const float* x   = (const float*)d_in[0];
  const float* ea  = (const float*)d_in[1];
  const int*   ei  = (const int*)d_in[2];
  const float* ew1 = (const float*)d_in[3];
  const float* eb1 = (const float*)d_in[4];
  const float* ew2 = (const float*)d_in[5];
  const float* eb2 = (const float*)d_in[6];
  const float* ewr = (const float*)d_in[7];
  const float* ebr = (const float*)d_in[8];
  const float* eg  = (const float*)d_in[9];
  const float* ebt = (const float*)d_in[10];
  const float* nw1 = (const float*)d_in[11];
  const float* nb1 = (const float*)d_in[12];
  const float* nw2 = (const float*)d_in[13];
  const float* nb2 = (const float*)d_in[14];
  const float* nwr = (const float*)d_in[15];
  const float* nbr = (const float*)d_in[16];
  const float* ng  = (const float*)d_in[17];
  const float* nbt = (const float*)d_in[18];

  char* ws = (char*)d_ws;
  float* agg  = (float*)ws;                   // NN*128 f32 = 25.6 MB
  int* cnt    = (int*)(ws + 25600000);        // contiguous with agg
  int* off    = cnt + NNP;
  int* cursor = off + NNP;
  int* idxflag = cursor + NNP;
  int* bsum   = idxflag + 64;                 // SCAN_B ints
  int* boff   = bsum + 256;                   // SCAN_B ints
  int4* edata = (int4*)(boff + 256);          // NE int4 = 12.8 MB
  unsigned short* rew1 = (unsigned short*)(edata + NE);
  unsigned short* rew2 = rew1 + 12*16*64*8;
  unsigned short* rewr = rew2 + 8*8*64*8;
  unsigned short* rnw1 = rewr + 12*8*64*8;
  unsigned short* rnw2 = rnw1 + 8*16*64*8;
  unsigned short* rnwr = rnw2 + 8*8*64*8;

  // agg and cnt are contiguous: single fused memset
  hipMemsetAsync(agg, 0, (size_t)NN * 128 * 4 + NNP * sizeof(int), stream);

  detect_idx<<<1, 64, 0, stream>>>(ei, idxflag);

  hist_kernel<<<(NE + 255) / 256, 256, 0, stream>>>(ei, idxflag, cnt);
  psum1<<<SCAN_B, 256, 0, stream>>>(cnt, bsum);
  psum2<<<1, 256, 0, stream>>>(bsum, boff);
  psum3<<<SCAN_B, 256, 0, stream>>>(cnt, boff, off, cursor);
  scatter_kernel<<<(NE + 255) / 256, 256, 0, stream>>>(ei, idxflag, cursor, edata);

  repack_all<<<152, 256, 0, stream>>>(ew1, ew2, ewr, nw1, nw2, nwr,
                                      rew1, rew2, rewr, rnw1, rnw2, rnwr);

  float* out_x = (float*)d_out;
  float* out_e = out_x + (size_t)NN * 128;

  (void)hipFuncSetAttribute(reinterpret_cast<const void*>(edge_kernel),
                            hipFuncAttributeMaxDynamicSharedMemorySize, 163840);
  (void)hipFuncSetAttribute(reinterpret_cast<const void*>(node_kernel),
                            hipFuncAttributeMaxDynamicSharedMemorySize, 163840);

  edge_kernel<<<NE / 64, 512, 49664, stream>>>(
      x, ea, edata, rew1, rew2, rewr, eb1, eb2, ebr, eg, ebt, out_e, agg);

  node_kernel<<<(NN + 63) / 64, 512, 36864, stream>>>(
      x, agg, rnw1, rnw2, rnwr, nb1, nb2, nbr, ng, nbt, out_x);
}

// Round 20
// 609.135 us; speedup vs baseline: 1.0175x; 1.0175x over previous
//
#include <hip/hip_runtime.h>
#include <hip/hip_bf16.h>
#include <stdint.h>

typedef __attribute__((ext_vector_type(8))) short short8;
typedef __attribute__((ext_vector_type(4))) float f32x4;

#define NN 50000
#define NNP 50048
#define NE 800000
#define SCAN_B 196   // ceil(50000/256)

__device__ __forceinline__ unsigned short f2bf(float f){
  union { unsigned int i; float f; } v; v.f = f;
  unsigned int u = v.i;
  u += 0x7fffu + ((u >> 16) & 1u);
  return (unsigned short)(u >> 16);
}

// fast silu: x * rcp(1+exp(-x))
__device__ __forceinline__ float fast_silu(float v){
  return v * __builtin_amdgcn_rcpf(1.f + __expf(-v));
}

// Detect whether edge_index is int64 (high 32-bit words all zero) or int32.
__global__ void detect_idx(const int* __restrict__ raw, int* __restrict__ flag){
  if (threadIdx.x == 0 && blockIdx.x == 0){
    int s = 0;
#pragma unroll
    for (int k = 1; k < 256; k += 2) s |= raw[k];
    *flag = (s == 0) ? 1 : 0;
  }
}

__device__ __forceinline__ int load_src(const int* ei, int is64, int e){
  return is64 ? ei[2 * e] : ei[e];
}
__device__ __forceinline__ int load_dst(const int* ei, int is64, int e){
  return is64 ? ei[2 * NE + 2 * e] : ei[NE + e];
}

// CSR pass 1: histogram of dst
__global__ void hist_kernel(const int* __restrict__ ei, const int* __restrict__ idxflag,
                            int* __restrict__ cnt){
  int e = blockIdx.x * 256 + threadIdx.x;
  if (e >= NE) return;
  atomicAdd(&cnt[load_dst(ei, *idxflag, e)], 1);
}

// Parallel scan, stage 1: per-block sums of 256 cnt entries.
__global__ void psum1(const int* __restrict__ cnt, int* __restrict__ bsum){
  __shared__ int ws[4];
  const int tid = threadIdx.x, lane = tid & 63, wid = tid >> 6;
  const int i = blockIdx.x * 256 + tid;
  int v = (i < NN) ? cnt[i] : 0;
#pragma unroll
  for (int o = 32; o >= 1; o >>= 1) v += __shfl_xor(v, o);
  if (lane == 0) ws[wid] = v;
  __syncthreads();
  if (tid == 0) bsum[blockIdx.x] = ws[0] + ws[1] + ws[2] + ws[3];
}

// Parallel scan, stage 2: exclusive scan of SCAN_B block sums.
__global__ void psum2(const int* __restrict__ bsum, int* __restrict__ boff){
  __shared__ int ws[4];
  const int tid = threadIdx.x, lane = tid & 63, wid = tid >> 6;
  int v = (tid < SCAN_B) ? bsum[tid] : 0;
  int s = v;
#pragma unroll
  for (int o = 1; o < 64; o <<= 1){
    int t = __shfl_up(s, o);
    if (lane >= o) s += t;
  }
  if (lane == 63) ws[wid] = s;
  __syncthreads();
  int add = 0;
#pragma unroll
  for (int q = 0; q < 4; ++q) add += (q < wid) ? ws[q] : 0;
  if (tid < SCAN_B) boff[tid] = add + s - v;   // exclusive
}

// Parallel scan, stage 3: writes off[i+1] (inclusive) AND cursor[i] (exclusive).
__global__ void psum3(const int* __restrict__ cnt, const int* __restrict__ boff,
                      int* __restrict__ off, int* __restrict__ cursor){
  __shared__ int ws[4];
  const int tid = threadIdx.x, lane = tid & 63, wid = tid >> 6;
  const int i = blockIdx.x * 256 + tid;
  int v = (i < NN) ? cnt[i] : 0;
  int s = v;
#pragma unroll
  for (int o = 1; o < 64; o <<= 1){
    int t = __shfl_up(s, o);
    if (lane >= o) s += t;
  }
  if (lane == 63) ws[wid] = s;
  __syncthreads();
  int add = boff[blockIdx.x];
#pragma unroll
  for (int q = 0; q < 4; ++q) add += (q < wid) ? ws[q] : 0;
  if (i < NN){
    off[i + 1] = add + s;
    cursor[i]  = add + s - v;   // exclusive prefix
  }
  if (i == 0) off[0] = 0;
}

// CSR pass 3: scatter full edge record {e, src, dst} by dst order.
__global__ void scatter_kernel(const int* __restrict__ ei, const int* __restrict__ idxflag,
                               int* __restrict__ cursor, int4* __restrict__ edata){
  int e = blockIdx.x * 256 + threadIdx.x;
  if (e >= NE) return;
  const int is64 = *idxflag;
  const int sn = load_src(ei, is64, e);
  const int dn = load_dst(ei, is64, e);
  const int pos = atomicAdd(&cursor[dn], 1);
  edata[pos] = make_int4(e, sn, dn, 0);
}

// Fused repack of all 6 weights into bf16 MFMA B-fragment layout.
__global__ void repack_all(
    const float* __restrict__ ew1, const float* __restrict__ ew2,
    const float* __restrict__ ewr, const float* __restrict__ nw1,
    const float* __restrict__ nw2, const float* __restrict__ nwr,
    unsigned short* __restrict__ rew1, unsigned short* __restrict__ rew2,
    unsigned short* __restrict__ rewr, unsigned short* __restrict__ rnw1,
    unsigned short* __restrict__ rnw2, unsigned short* __restrict__ rnwr)
{
  const int b = blockIdx.x;
  const float* W; unsigned short* out; int K, N, base;
  if (b < 48)       { W = ew1; out = rew1; K = 384; N = 256; base = 0;   }
  else if (b < 64)  { W = ew2; out = rew2; K = 256; N = 128; base = 48;  }
  else if (b < 88)  { W = ewr; out = rewr; K = 384; N = 128; base = 64;  }
  else if (b < 120) { W = nw1; out = rnw1; K = 256; N = 256; base = 88;  }
  else if (b < 136) { W = nw2; out = rnw2; K = 256; N = 128; base = 120; }
  else              { W = nwr; out = rnwr; K = 256; N = 128; base = 136; }
  int t = (b - base) * 256 + threadIdx.x;
  int lane = t & 63;
  int frag = t >> 6;
  int nts = N >> 4;
  int nt = frag % nts;
  int kt = frag / nts;
  if (kt >= (K >> 5)) return;
  int r0 = kt * 32 + 8 * (lane >> 4);
  int c  = nt * 16 + (lane & 15);
  short8 v;
#pragma unroll
  for (int j = 0; j < 8; ++j) v[j] = (short)f2bf(W[(size_t)(r0 + j) * N + c]);
  *(short8*)(out + (size_t)t * 8) = v;
}

__device__ __forceinline__ short8 cvt8(const float* p){
  f32x4 a = *(const f32x4*)(p);
  f32x4 b = *(const f32x4*)(p + 4);
  union { short8 s; __hip_bfloat162 h[4]; } u;
  u.h[0] = __float22bfloat162_rn(make_float2(a[0], a[1]));
  u.h[1] = __float22bfloat162_rn(make_float2(a[2], a[3]));
  u.h[2] = __float22bfloat162_rn(make_float2(b[0], b[1]));
  u.h[3] = __float22bfloat162_rn(make_float2(b[2], b[3]));
  return u.s;
}

// Bijective XCD-chunked swizzle (m204 form)
__device__ __forceinline__ int xcd_swizzle(int bid, int nwg){
  const int q = nwg >> 3, r = nwg & 7;
  const int xcd = bid & 7, idx = bid >> 3;
  return (xcd < r) ? xcd * (q + 1) + idx : r * (q + 1) + (xcd - r) * q + idx;
}

// ---------------- Edge kernel (measured-best: R18 structure) ---------------
__global__ __launch_bounds__(512, 4) void edge_kernel(
    const float* __restrict__ x,
    const float* __restrict__ ea,
    const int4* __restrict__ edata,
    const unsigned short* __restrict__ rw1,
    const unsigned short* __restrict__ rw2,
    const unsigned short* __restrict__ rwr,
    const float* __restrict__ b1,
    const float* __restrict__ b2,
    const float* __restrict__ br,
    const float* __restrict__ gam,
    const float* __restrict__ bet,
    float* __restrict__ oute,
    float* __restrict__ agg)
{
  extern __shared__ char smem[];
  unsigned short* A = (unsigned short*)smem;        // [4][12][64][8] bf16 = 48KB
  unsigned short* H = (unsigned short*)smem;        // [4][8][64][8]  = 32KB (alias)
  float* pf2    = (float*)smem;                     // [64 rows][132] (alias)
  float* pfstat = (float*)(smem + 34816);           // [64][2]
  int*   dst_lds  = (int*)(smem + 49152);           // [64]  beyond A
  int*   eidx_lds = (int*)(smem + 49408);           // [64]  beyond A

  const int tid  = threadIdx.x;
  const int lane = tid & 63;
  const int w    = tid >> 6;
  const int q0   = xcd_swizzle(blockIdx.x, NE / 64) * 64;

  {
    const int row = lane;
    const int4 ed = edata[q0 + row];    // single 16B load: {e, sn, dn, 0}
    const int e = ed.x, sn = ed.y, dn = ed.z;
    if (tid < 64){ dst_lds[row] = dn; eidx_lds[row] = e; }
    const int m   = row >> 4;
    const int rl  = row & 15;
#pragma unroll
    for (int it = 0; it < 6; ++it){
      const int seg = w + 8 * it;
      const float* p;
      if (seg < 16)      p = ea + (size_t)e  * 128 + seg * 8;
      else if (seg < 32) p = x  + (size_t)sn * 128 + (seg - 16) * 8;
      else               p = x  + (size_t)dn * 128 + (seg - 32) * 8;
      short8 v = cvt8(p);
      const int ks = seg >> 2;
      const int lp = rl + 16 * (seg & 3);
      *(short8*)(A + (((m * 12 + ks) * 64) + lp) * 8) = v;
    }
  }

  short8 cb1[2], cbr, nb1[2], nbr;
#pragma unroll
  for (int nti = 0; nti < 2; ++nti)
    cb1[nti] = *(const short8*)(rw1 + ((size_t)((w * 2 + nti) * 64 + lane)) * 8);
  cbr = *(const short8*)(rwr + ((size_t)(w * 64 + lane)) * 8);

  __syncthreads();

  f32x4 acc1[2][4];
  f32x4 accr[4];
#pragma unroll
  for (int i = 0; i < 2; ++i)
#pragma unroll
    for (int j = 0; j < 4; ++j) acc1[i][j] = (f32x4){0.f,0.f,0.f,0.f};
#pragma unroll
  for (int j = 0; j < 4; ++j) accr[j] = (f32x4){0.f,0.f,0.f,0.f};

#pragma unroll
  for (int ks = 0; ks < 12; ++ks){
    if (ks < 11){
#pragma unroll
      for (int nti = 0; nti < 2; ++nti)
        nb1[nti] = *(const short8*)(rw1 + ((size_t)(((ks + 1) * 16 + w * 2 + nti) * 64 + lane)) * 8);
      nbr = *(const short8*)(rwr + ((size_t)(((ks + 1) * 8 + w) * 64 + lane)) * 8);
    }
    short8 af[4];
#pragma unroll
    for (int m = 0; m < 4; ++m)
      af[m] = *(const short8*)(A + (((m * 12 + ks) * 64) + lane) * 8);
    __builtin_amdgcn_s_setprio(1);
#pragma unroll
    for (int nti = 0; nti < 2; ++nti)
#pragma unroll
      for (int m = 0; m < 4; ++m)
        acc1[nti][m] = __builtin_amdgcn_mfma_f32_16x16x32_bf16(af[m], cb1[nti], acc1[nti][m], 0, 0, 0);
#pragma unroll
    for (int m = 0; m < 4; ++m)
      accr[m] = __builtin_amdgcn_mfma_f32_16x16x32_bf16(af[m], cbr, accr[m], 0, 0, 0);
    __builtin_amdgcn_s_setprio(0);
    if (ks < 11){
#pragma unroll
      for (int nti = 0; nti < 2; ++nti) cb1[nti] = nb1[nti];
      cbr = nbr;
    }
  }

  short8 cb2, nb2;
  cb2 = *(const short8*)(rw2 + ((size_t)(w * 64 + lane)) * 8);

  __syncthreads();

#pragma unroll
  for (int nti = 0; nti < 2; ++nti){
    const int nt  = w * 2 + nti;
    const int col = nt * 16 + (lane & 15);
    const float bias = b1[col];
    const int ks  = nt >> 1;
    const int lpb = 4 * (lane >> 4) + 16 * (2 * (nt & 1) + ((lane >> 3) & 1));
    const int t   = lane & 7;
#pragma unroll
    for (int m = 0; m < 4; ++m){
#pragma unroll
      for (int r = 0; r < 4; ++r){
        const float v = fast_silu(acc1[nti][m][r] + bias);
        H[(((m * 8 + ks) * 64) + lpb + r) * 8 + t] = f2bf(v);
      }
    }
  }
  __syncthreads();

#pragma unroll
  for (int ks = 0; ks < 8; ++ks){
    if (ks < 7)
      nb2 = *(const short8*)(rw2 + ((size_t)(((ks + 1) * 8 + w) * 64 + lane)) * 8);
    short8 hf[4];
#pragma unroll
    for (int m = 0; m < 4; ++m)
      hf[m] = *(const short8*)(H + (((m * 8 + ks) * 64) + lane) * 8);
    __builtin_amdgcn_s_setprio(1);
#pragma unroll
    for (int m = 0; m < 4; ++m)
      accr[m] = __builtin_amdgcn_mfma_f32_16x16x32_bf16(hf[m], cb2, accr[m], 0, 0, 0);
    __builtin_amdgcn_s_setprio(0);
    if (ks < 7) cb2 = nb2;
  }

  const int l15 = lane & 15;
  const int g   = lane >> 4;
  const int col = w * 16 + l15;
  const float bb  = b2[col] + br[col];
  const float gma = gam[col];
  const float bt  = bet[col];
  float vout[4][4];
#pragma unroll
  for (int m = 0; m < 4; ++m)
#pragma unroll
    for (int r = 0; r < 4; ++r)
      vout[m][r] = accr[m][r] + bb;

  __syncthreads();
#pragma unroll
  for (int m = 0; m < 4; ++m)
#pragma unroll
    for (int r = 0; r < 4; ++r)
      pf2[(m * 16 + g * 4 + r) * 132 + col] = vout[m][r];
  __syncthreads();

  {
    const int row = tid >> 3;
    const int cb  = tid & 7;
    const float* pr = pf2 + row * 132 + cb * 16;
    f32x4 a0 = *(const f32x4*)(pr);
    f32x4 a1 = *(const f32x4*)(pr + 4);
    f32x4 a2 = *(const f32x4*)(pr + 8);
    f32x4 a3 = *(const f32x4*)(pr + 12);
    float s1 = 0.f, s2 = 0.f;
#pragma unroll
    for (int j = 0; j < 4; ++j){
      s1 += a0[j] + a1[j] + a2[j] + a3[j];
      s2 += a0[j]*a0[j] + a1[j]*a1[j] + a2[j]*a2[j] + a3[j]*a3[j];
    }
#pragma unroll
    for (int off = 1; off < 8; off <<= 1){
      s1 += __shfl_xor(s1, off);
      s2 += __shfl_xor(s2, off);
    }
    if (cb == 0){
      const float mean = s1 * (1.f/128.f);
      const float var  = s2 * (1.f/128.f) - mean * mean;
      pfstat[row * 2 + 0] = mean;
      pfstat[row * 2 + 1] = rsqrtf(var + 1e-5f);
    }
  }
  __syncthreads();

  // apply LN ONCE: nt-store oute + post-LN back to pf2
#pragma unroll
  for (int m = 0; m < 4; ++m)
#pragma unroll
    for (int r = 0; r < 4; ++r){
      const int row = m * 16 + g * 4 + r;
      const float2 st = *(const float2*)(pfstat + row * 2);
      const float val = (vout[m][r] - st.x) * st.y * gma + bt;
      __builtin_nontemporal_store(val, &oute[(size_t)eidx_lds[row] * 128 + col]);
      pf2[row * 132 + col] = val;
    }
  __syncthreads();

  { // segment reduction: pure adds over post-LN pf2
    const int colA = tid & 127;
    const int q4   = tid >> 7;
    int   cur = dst_lds[q4 * 16];
    float run = 0.f;
#pragma unroll
    for (int j = 0; j < 16; ++j){
      const int row = q4 * 16 + j;
      const int dn  = dst_lds[row];
      const float v = pf2[row * 132 + colA];
      if (dn != cur){
        atomicAdd(&agg[(size_t)cur * 128 + colA], run);
        run = 0.f; cur = dn;
      }
      run += v;
    }
    atomicAdd(&agg[(size_t)cur * 128 + colA], run);
  }
}

// ---------------- Node kernel (R18 structure) ------------------------------
__global__ __launch_bounds__(512, 4) void node_kernel(
    const float* __restrict__ x,
    const float* __restrict__ agg,
    const unsigned short* __restrict__ rw1,
    const unsigned short* __restrict__ rw2,
    const unsigned short* __restrict__ rwr,
    const float* __restrict__ b1,
    const float* __restrict__ b2,
    const float* __restrict__ br,
    const float* __restrict__ gam,
    const float* __restrict__ bet,
    float* __restrict__ outx)
{
  extern __shared__ char smem[];
  unsigned short* A = (unsigned short*)smem;
  unsigned short* H = (unsigned short*)smem;
  float* pf2    = (float*)smem;
  float* pfstat = (float*)(smem + 34816);

  const int tid  = threadIdx.x;
  const int lane = tid & 63;
  const int w    = tid >> 6;
  const int n0   = blockIdx.x * 64;

  {
    const int row = lane;
    const int n   = n0 + row;
    const bool ok = (n < NN);
    const int m   = row >> 4;
    const int rl  = row & 15;
#pragma unroll
    for (int it = 0; it < 4; ++it){
      const int seg = w + 8 * it;
      short8 v;
      if (!ok){
        v = (short8){0,0,0,0,0,0,0,0};
      } else {
        const float* p = (seg < 16) ? (x + (size_t)n * 128 + seg * 8)
                                    : (agg + (size_t)n * 128 + (seg - 16) * 8);
        v = cvt8(p);
      }
      const int ks = seg >> 2;
      const int lp = rl + 16 * (seg & 3);
      *(short8*)(A + (((m * 8 + ks) * 64) + lp) * 8) = v;
    }
  }

  short8 cb1[2], cbr, nb1[2], nbr;
#pragma unroll
  for (int nti = 0; nti < 2; ++nti)
    cb1[nti] = *(const short8*)(rw1 + ((size_t)((w * 2 + nti) * 64 + lane)) * 8);
  cbr = *(const short8*)(rwr + ((size_t)(w * 64 + lane)) * 8);

  __syncthreads();

  f32x4 acc1[2][4];
  f32x4 accr[4];
#pragma unroll
  for (int i = 0; i < 2; ++i)
#pragma unroll
    for (int j = 0; j < 4; ++j) acc1[i][j] = (f32x4){0.f,0.f,0.f,0.f};
#pragma unroll
  for (int j = 0; j < 4; ++j) accr[j] = (f32x4){0.f,0.f,0.f,0.f};

#pragma unroll
  for (int ks = 0; ks < 8; ++ks){
    if (ks < 7){
#pragma unroll
      for (int nti = 0; nti < 2; ++nti)
        nb1[nti] = *(const short8*)(rw1 + ((size_t)(((ks + 1) * 16 + w * 2 + nti) * 64 + lane)) * 8);
      nbr = *(const short8*)(rwr + ((size_t)(((ks + 1) * 8 + w) * 64 + lane)) * 8);
    }
    short8 af[4];
#pragma unroll
    for (int m = 0; m < 4; ++m)
      af[m] = *(const short8*)(A + (((m * 8 + ks) * 64) + lane) * 8);
    __builtin_amdgcn_s_setprio(1);
#pragma unroll
    for (int nti = 0; nti < 2; ++nti)
#pragma unroll
      for (int m = 0; m < 4; ++m)
        acc1[nti][m] = __builtin_amdgcn_mfma_f32_16x16x32_bf16(af[m], cb1[nti], acc1[nti][m], 0, 0, 0);
#pragma unroll
    for (int m = 0; m < 4; ++m)
      accr[m] = __builtin_amdgcn_mfma_f32_16x16x32_bf16(af[m], cbr, accr[m], 0, 0, 0);
    __builtin_amdgcn_s_setprio(0);
    if (ks < 7){
#pragma unroll
      for (int nti = 0; nti < 2; ++nti) cb1[nti] = nb1[nti];
      cbr = nbr;
    }
  }

  short8 cb2, nb2;
  cb2 = *(const short8*)(rw2 + ((size_t)(w * 64 + lane)) * 8);

  __syncthreads();

#pragma unroll
  for (int nti = 0; nti < 2; ++nti){
    const int nt  = w * 2 + nti;
    const int col = nt * 16 + (lane & 15);
    const float bias = b1[col];
    const int ks  = nt >> 1;
    const int lpb = 4 * (lane >> 4) + 16 * (2 * (nt & 1) + ((lane >> 3) & 1));
    const int t   = lane & 7;
#pragma unroll
    for (int m = 0; m < 4; ++m){
#pragma unroll
      for (int r = 0; r < 4; ++r){
        const float v = fast_silu(acc1[nti][m][r] + bias);
        H[(((m * 8 + ks) * 64) + lpb + r) * 8 + t] = f2bf(v);
      }
    }
  }
  __syncthreads();

#pragma unroll
  for (int ks = 0; ks < 8; ++ks){
    if (ks < 7)
      nb2 = *(const short8*)(rw2 + ((size_t)(((ks + 1) * 8 + w) * 64 + lane)) * 8);
    short8 hf[4];
#pragma unroll
    for (int m = 0; m < 4; ++m)
      hf[m] = *(const short8*)(H + (((m * 8 + ks) * 64) + lane) * 8);
    __builtin_amdgcn_s_setprio(1);
#pragma unroll
    for (int m = 0; m < 4; ++m)
      accr[m] = __builtin_amdgcn_mfma_f32_16x16x32_bf16(hf[m], cb2, accr[m], 0, 0, 0);
    __builtin_amdgcn_s_setprio(0);
    if (ks < 7) cb2 = nb2;
  }

  const int l15 = lane & 15;
  const int g   = lane >> 4;
  const int col = w * 16 + l15;
  const float bb  = b2[col] + br[col];
  const float gma = gam[col];
  const float bt  = bet[col];
  float vout[4][4];
#pragma unroll
  for (int m = 0; m < 4; ++m)
#pragma unroll
    for (int r = 0; r < 4; ++r)
      vout[m][r] = accr[m][r] + bb;

  __syncthreads();
#pragma unroll
  for (int m = 0; m < 4; ++m)
#pragma unroll
    for (int r = 0; r < 4; ++r)
      pf2[(m * 16 + g * 4 + r) * 132 + col] = vout[m][r];
  __syncthreads();

  {
    const int row = tid >> 3;
    const int cb  = tid & 7;
    const float* pr = pf2 + row * 132 + cb * 16;
    f32x4 a0 = *(const f32x4*)(pr);
    f32x4 a1 = *(const f32x4*)(pr + 4);
    f32x4 a2 = *(const f32x4*)(pr + 8);
    f32x4 a3 = *(const f32x4*)(pr + 12);
    float s1 = 0.f, s2 = 0.f;
#pragma unroll
    for (int j = 0; j < 4; ++j){
      s1 += a0[j] + a1[j] + a2[j] + a3[j];
      s2 += a0[j]*a0[j] + a1[j]*a1[j] + a2[j]*a2[j] + a3[j]*a3[j];
    }
#pragma unroll
    for (int off2 = 1; off2 < 8; off2 <<= 1){
      s1 += __shfl_xor(s1, off2);
      s2 += __shfl_xor(s2, off2);
    }
    if (cb == 0){
      const float mean = s1 * (1.f/128.f);
      const float var  = s2 * (1.f/128.f) - mean * mean;
      pfstat[row * 2 + 0] = mean;
      pfstat[row * 2 + 1] = rsqrtf(var + 1e-5f);
    }
  }
  __syncthreads();

#pragma unroll
  for (int m = 0; m < 4; ++m)
#pragma unroll
    for (int r = 0; r < 4; ++r){
      const int row = m * 16 + g * 4 + r;
      const int n = n0 + row;
      if (n >= NN) continue;
      const float2 st = *(const float2*)(pfstat + row * 2);
      const float val = (vout[m][r] - st.x) * st.y * gma + bt;
      __builtin_nontemporal_store(val, &outx[(size_t)n * 128 + col]);
    }
}

extern "C" void kernel_launch(void* const* d_in, const int* in_sizes, int n_in,
                              void* d_out, int out_size, void* d_ws, size_t ws_size,
                              hipStream_t stream)
{
  const float* x   = (const float*)d_in[0];
  const float* ea  = (const float*)d_in[1];
  const int*   ei  = (const int*)d_in[2];
  const float* ew1 = (const float*)d_in[3];
  const float* eb1 = (const float*)d_in[4];
  const float* ew2 = (const float*)d_in[5];
  const float* eb2 = (const float*)d_in[6];
  const float* ewr = (const float*)d_in[7];
  const float* ebr = (const float*)d_in[8];
  const float* eg  = (const float*)d_in[9];
  const float* ebt = (const float*)d_in[10];
  const float* nw1 = (const float*)d_in[11];
  const float* nb1 = (const float*)d_in[12];
  const float* nw2 = (const float*)d_in[13];
  const float* nb2 = (const float*)d_in[14];
  const float* nwr = (const float*)d_in[15];
  const float* nbr = (const float*)d_in[16];
  const float* ng  = (const float*)d_in[17];
  const float* nbt = (const float*)d_in[18];

  char* ws = (char*)d_ws;
  float* agg  = (float*)ws;                   // NN*128 f32 = 25.6 MB
  int* cnt    = (int*)(ws + 25600000);
  int* off    = cnt + NNP;
  int* cursor = off + NNP;
  int* idxflag = cursor + NNP;
  int* bsum   = idxflag + 64;                 // SCAN_B ints
  int* boff   = bsum + 256;                   // SCAN_B ints
  int4* edata = (int4*)(boff + 256);          // NE int4 = 12.8 MB
  unsigned short* rew1 = (unsigned short*)(edata + NE);
  unsigned short* rew2 = rew1 + 12*16*64*8;
  unsigned short* rewr = rew2 + 8*8*64*8;
  unsigned short* rnw1 = rewr + 12*8*64*8;
  unsigned short* rnw2 = rnw1 + 8*16*64*8;
  unsigned short* rnwr = rnw2 + 8*8*64*8;

  hipMemsetAsync(agg, 0, (size_t)NN * 128 * 4, stream);
  hipMemsetAsync(cnt, 0, NNP * sizeof(int), stream);

  detect_idx<<<1, 64, 0, stream>>>(ei, idxflag);

  hist_kernel<<<(NE + 255) / 256, 256, 0, stream>>>(ei, idxflag, cnt);
  psum1<<<SCAN_B, 256, 0, stream>>>(cnt, bsum);
  psum2<<<1, 256, 0, stream>>>(bsum, boff);
  psum3<<<SCAN_B, 256, 0, stream>>>(cnt, boff, off, cursor);
  scatter_kernel<<<(NE + 255) / 256, 256, 0, stream>>>(ei, idxflag, cursor, edata);

  repack_all<<<152, 256, 0, stream>>>(ew1, ew2, ewr, nw1, nw2, nwr,
                                      rew1, rew2, rewr, rnw1, rnw2, rnwr);

  float* out_x = (float*)d_out;
  float* out_e = out_x + (size_t)NN * 128;

  (void)hipFuncSetAttribute(reinterpret_cast<const void*>(edge_kernel),
                            hipFuncAttributeMaxDynamicSharedMemorySize, 163840);
  (void)hipFuncSetAttribute(reinterpret_cast<const void*>(node_kernel),
                            hipFuncAttributeMaxDynamicSharedMemorySize, 163840);

  edge_kernel<<<NE / 64, 512, 49664, stream>>>(
      x, ea, edata, rew1, rew2, rewr, eb1, eb2, ebr, eg, ebt, out_e, agg);

  node_kernel<<<(NN + 63) / 64, 512, 36864, stream>>>(
      x, agg, rnw1, rnw2, rnwr, nb1, nb2, nbr, ng, nbt, out_x);
}